// Round 1
// baseline (1494.606 us; speedup 1.0000x reference)
//
#include <hip/hip_runtime.h>
#include <hip/hip_bf16.h>

#define NB 16
#define TT 2048
#define CC 384    // embedding dim == head dim

typedef short bf16x8 __attribute__((ext_vector_type(8)));
typedef float f32x4 __attribute__((ext_vector_type(4)));

static __device__ __forceinline__ short f2bf(float f) {
  union { __hip_bfloat16 h; short s; } u;
  u.h = __float2bfloat16(f);
  return u.s;
}

// ---------------------------------------------------------------------------
// Projection: Q = x@Wq, K = x@Wk, V = x@Wv. fp32 accumulate, bf16 out.
// Q,K stored [b][t][384]; V stored transposed Vt[b][384][2048] (PV B-operand
// needs head-dim-major rows).
// Block: 384 threads (thread j owns output column j), 16 t-rows per block.
// ---------------------------------------------------------------------------
__global__ __launch_bounds__(384)
void proj_kernel(const float* __restrict__ x,
                 const float* __restrict__ Wq,
                 const float* __restrict__ Wk,
                 const float* __restrict__ Wv,
                 short* __restrict__ Q,
                 short* __restrict__ K,
                 short* __restrict__ Vt) {
  __shared__ float xs[16 * CC];        // 24 KB
  __shared__ short vtile[CC * 24];     // 18 KB, stride 24 shorts = 48 B (16B-aligned rows)
  const int blk = blockIdx.x;          // NB * TT/16 blocks
  const int b  = blk / (TT / 16);
  const int t0 = (blk % (TT / 16)) * 16;
  const int j  = threadIdx.x;          // 0..383

  const float* xb = x + ((size_t)b * TT + t0) * CC;
  #pragma unroll
  for (int r = 0; r < 16; ++r) xs[r * CC + j] = xb[r * CC + j];
  __syncthreads();

  float aq[16], ak[16], av[16];
  #pragma unroll
  for (int r = 0; r < 16; ++r) { aq[r] = 0.f; ak[r] = 0.f; av[r] = 0.f; }

  #pragma unroll 2
  for (int i = 0; i < CC; i += 2) {
    const float wq0 = Wq[i * CC + j];
    const float wk0 = Wk[i * CC + j];
    const float wv0 = Wv[i * CC + j];
    const float wq1 = Wq[(i + 1) * CC + j];
    const float wk1 = Wk[(i + 1) * CC + j];
    const float wv1 = Wv[(i + 1) * CC + j];
    #pragma unroll
    for (int r = 0; r < 16; ++r) {
      const float2 xv = *(const float2*)&xs[r * CC + i];
      aq[r] += xv.x * wq0; aq[r] += xv.y * wq1;
      ak[r] += xv.x * wk0; ak[r] += xv.y * wk1;
      av[r] += xv.x * wv0; av[r] += xv.y * wv1;
    }
  }

  // Q, K: coalesced bf16 stores
  #pragma unroll
  for (int r = 0; r < 16; ++r) {
    Q[((size_t)b * TT + t0 + r) * CC + j] = f2bf(aq[r]);
    K[((size_t)b * TT + t0 + r) * CC + j] = f2bf(ak[r]);
  }
  // V: transpose 384x16 tile through LDS, then 16B stores into Vt rows
  #pragma unroll
  for (int r = 0; r < 16; ++r) vtile[j * 24 + r] = f2bf(av[r]);
  __syncthreads();
  #pragma unroll
  for (int it = 0; it < 2; ++it) {
    const int p = j + it * CC;       // 0..767
    const int d = p >> 1;
    const int half = p & 1;
    const uint4 v = *(const uint4*)&vtile[d * 24 + half * 8];
    *(uint4*)(Vt + ((size_t)b * CC + d) * TT + t0 + half * 8) = v;
  }
}

// ---------------------------------------------------------------------------
// Flash attention, causal, single head. bf16 MFMA 16x16x32, fp32 softmax/acc.
// Block: 256 threads = 4 waves; each wave owns 16 queries, streams keys in
// chunks of 32 with online softmax. No inter-wave deps -> no barriers.
// MFMA layouts (guide §3, m89/m91/m120-verified):
//   A-frag:  A[m = lane&15][k = (lane>>4)*8 + j]   (8 contiguous K elems)
//   B-frag:  B^T[n = lane&15][k = (lane>>4)*8 + j] (operand given as [N][K])
//   C/D:     row m = (lane>>4)*4 + reg, col n = lane&15
// ---------------------------------------------------------------------------
__global__ __launch_bounds__(256)
void attn_kernel(const short* __restrict__ Q,
                 const short* __restrict__ K,
                 const short* __restrict__ Vt,
                 float* __restrict__ out) {
  const int blk  = blockIdx.x;              // NB * TT/64
  const int b    = blk / (TT / 64);
  const int q0b  = (blk % (TT / 64)) * 64;
  const int wave = threadIdx.x >> 6;
  const int lane = threadIdx.x & 63;
  const int lane15 = lane & 15;
  const int quad = lane >> 4;
  const int q0 = q0b + wave * 16;           // wave's first query

  __shared__ short pa[4][16 * 40];          // per-wave P in A-layout, padded rows
  short* pw = pa[wave];

  // Q fragments: 12 k-steps of 32, resident in registers
  bf16x8 qf[12];
  const short* qp = Q + ((size_t)b * TT + q0 + lane15) * CC + quad * 8;
  #pragma unroll
  for (int ks = 0; ks < 12; ++ks) qf[ks] = *(const bf16x8*)(qp + ks * 32);

  f32x4 o[24];
  #pragma unroll
  for (int n = 0; n < 24; ++n) o[n] = f32x4{0.f, 0.f, 0.f, 0.f};
  float m[4], l[4];
  #pragma unroll
  for (int r = 0; r < 4; ++r) { m[r] = -INFINITY; l[r] = 0.f; }

  const float scale = 0.051031036307982884f;   // 384^-0.5
  const short* kb  = K  + (size_t)b * TT * CC;
  const short* vtb = Vt + (size_t)b * CC * TT;
  const int nchunk = (q0 + 16 + 31) >> 5;      // keys 0 .. q_max inclusive

  for (int kc = 0; kc < nchunk; ++kc) {
    const int k0 = kc * 32;
    // ---- S = Q K^T for 16 queries x 32 keys
    f32x4 s0 = f32x4{0.f, 0.f, 0.f, 0.f};
    f32x4 s1 = f32x4{0.f, 0.f, 0.f, 0.f};
    const short* kp = kb + (size_t)(k0 + lane15) * CC + quad * 8;
    #pragma unroll
    for (int ks = 0; ks < 12; ++ks) {
      const bf16x8 b0 = *(const bf16x8*)(kp + ks * 32);
      const bf16x8 b1 = *(const bf16x8*)(kp + 16 * CC + ks * 32);
      s0 = __builtin_amdgcn_mfma_f32_16x16x32_bf16(qf[ks], b0, s0, 0, 0, 0);
      s1 = __builtin_amdgcn_mfma_f32_16x16x32_bf16(qf[ks], b1, s1, 0, 0, 0);
    }
    // ---- scale + causal mask + row max
    float mx[4];
    #pragma unroll
    for (int r = 0; r < 4; ++r) {
      const int qg = q0 + quad * 4 + r;
      float a = s0[r] * scale;
      float c = s1[r] * scale;
      if (k0 + lane15 > qg)      a = -INFINITY;
      if (k0 + 16 + lane15 > qg) c = -INFINITY;
      s0[r] = a; s1[r] = c;
      float v = fmaxf(a, c);
      v = fmaxf(v, __shfl_xor(v, 1));
      v = fmaxf(v, __shfl_xor(v, 2));
      v = fmaxf(v, __shfl_xor(v, 4));
      v = fmaxf(v, __shfl_xor(v, 8));
      mx[r] = v;
    }
    // ---- online softmax update
    float alpha[4];
    #pragma unroll
    for (int r = 0; r < 4; ++r) {
      const float mn = fmaxf(m[r], mx[r]);
      alpha[r] = __expf(m[r] - mn);
      m[r] = mn;
      const float p0 = __expf(s0[r] - mn);
      const float p1 = __expf(s1[r] - mn);
      s0[r] = p0; s1[r] = p1;
      float rs = p0 + p1;
      rs += __shfl_xor(rs, 1);
      rs += __shfl_xor(rs, 2);
      rs += __shfl_xor(rs, 4);
      rs += __shfl_xor(rs, 8);
      l[r] = l[r] * alpha[r] + rs;
    }
    const bool need = (alpha[0] < 1.f) | (alpha[1] < 1.f) |
                      (alpha[2] < 1.f) | (alpha[3] < 1.f);
    if (__any(need)) {
      #pragma unroll
      for (int n = 0; n < 24; ++n) {
        #pragma unroll
        for (int r = 0; r < 4; ++r) o[n][r] *= alpha[r];
      }
    }
    // ---- P: C-layout -> A-layout via LDS (wave-private, in-order DS pipe)
    #pragma unroll
    for (int r = 0; r < 4; ++r) {
      pw[(quad * 4 + r) * 40 + lane15]      = f2bf(s0[r]);
      pw[(quad * 4 + r) * 40 + 16 + lane15] = f2bf(s1[r]);
    }
    const bf16x8 pf = *(const bf16x8*)(pw + lane15 * 40 + quad * 8);
    // ---- O += P V  (B-operand rows = head dims, from Vt)
    const short* vp = vtb + (size_t)lane15 * TT + k0 + quad * 8;
    #pragma unroll
    for (int n = 0; n < 24; ++n) {
      const bf16x8 vf = *(const bf16x8*)(vp + (size_t)n * 16 * TT);
      o[n] = __builtin_amdgcn_mfma_f32_16x16x32_bf16(pf, vf, o[n], 0, 0, 0);
    }
  }

  // ---- epilogue: normalize and store fp32
  float linv[4];
  #pragma unroll
  for (int r = 0; r < 4; ++r) linv[r] = 1.f / l[r];
  float* ob = out + ((size_t)b * TT + q0) * CC;
  #pragma unroll
  for (int n = 0; n < 24; ++n) {
    #pragma unroll
    for (int r = 0; r < 4; ++r) {
      ob[(size_t)(quad * 4 + r) * CC + n * 16 + lane15] = o[n][r] * linv[r];
    }
  }
}

extern "C" void kernel_launch(void* const* d_in, const int* in_sizes, int n_in,
                              void* d_out, int out_size, void* d_ws, size_t ws_size,
                              hipStream_t stream) {
  const float* x  = (const float*)d_in[0];
  const float* Wq = (const float*)d_in[1];
  const float* Wk = (const float*)d_in[2];
  const float* Wv = (const float*)d_in[3];
  float* out = (float*)d_out;

  const size_t QS = (size_t)NB * TT * CC;
  short* Q  = (short*)d_ws;
  short* K  = Q + QS;
  short* Vt = K + QS;   // needs 3*QS*2 = 75.5 MB of ws

  hipLaunchKernelGGL(proj_kernel, dim3(NB * TT / 16), dim3(CC), 0, stream,
                     x, Wq, Wk, Wv, Q, K, Vt);
  hipLaunchKernelGGL(attn_kernel, dim3(NB * TT / 64), dim3(256), 0, stream,
                     Q, K, Vt, out);
}

// Round 3
// 461.621 us; speedup vs baseline: 3.2377x; 3.2377x over previous
//
#include <hip/hip_runtime.h>
#include <hip/hip_bf16.h>

#define NB 16
#define TT 2048
#define CC 384

typedef short bf16x8 __attribute__((ext_vector_type(8)));
typedef float f32x4 __attribute__((ext_vector_type(4)));

static __device__ __forceinline__ short f2bf(float f) {
  union { __hip_bfloat16 h; short s; } u;
  u.h = __float2bfloat16(f);
  return u.s;
}

// ---------------------------------------------------------------------------
// x (fp32) -> xb (bf16), flat
// ---------------------------------------------------------------------------
__global__ __launch_bounds__(256)
void conv_x(const float* __restrict__ x, short* __restrict__ xb, int n4) {
  const int i = blockIdx.x * 256 + threadIdx.x;
  if (i < n4) {
    const float4 v = ((const float4*)x)[i];
    short4 o;
    o.x = f2bf(v.x); o.y = f2bf(v.y); o.z = f2bf(v.z); o.w = f2bf(v.w);
    ((short4*)xb)[i] = o;
  }
}

// ---------------------------------------------------------------------------
// W[3] (fp32 [C][H]) -> Wbt (bf16 [3][n=H][k=C])  (transposed for LDS staging)
// ---------------------------------------------------------------------------
__global__ __launch_bounds__(384)
void conv_wt(const float* __restrict__ Wq, const float* __restrict__ Wk,
             const float* __restrict__ Wv, short* __restrict__ Wbt) {
  const int w = blockIdx.x / CC;
  const int n = blockIdx.x % CC;
  const int k = threadIdx.x;
  const float* W = (w == 0) ? Wq : (w == 1) ? Wk : Wv;
  Wbt[((size_t)w * CC + n) * CC + k] = f2bf(W[(size_t)k * CC + n]);
}

// ---------------------------------------------------------------------------
// Fused QKV projection GEMM: [32768 x 384] x [384 x 1152] bf16 MFMA.
// Grid = 256 m-tiles x 9 n-tiles. Block 256 thr / 4 waves, tile 128x128,
// BK=32, LDS-staged (padded rows: stride 80 B -> 2-way bank alias = free).
// n-tiles 0-2 -> Q, 3-5 -> K (row-major bf16), 6-8 -> V transposed into
// Vt[b][d][t] via LDS transpose epilogue.
// ---------------------------------------------------------------------------
__global__ __launch_bounds__(256, 3)
void proj_gemm(const short* __restrict__ xb, const short* __restrict__ Wbt,
               short* __restrict__ Q, short* __restrict__ K,
               short* __restrict__ Vt) {
  __shared__ char smem[34816];           // staging (2x10240) U epilogue (34816)
  short* As = (short*)smem;              // [128][40] shorts (32 data + 8 pad)
  short* Bs = (short*)(smem + 10240);    // [128][40]
  short* Es = (short*)smem;              // epilogue [128][136]

  const int mt = blockIdx.x & 255;
  const int nt = blockIdx.x >> 8;        // 0..8
  const int wsel = nt / 3;               // 0=Q,1=K,2=V
  const int nc0 = (nt % 3) * 128;
  const int tid = threadIdx.x;
  const int wave = tid >> 6, lane = tid & 63;
  const int l15 = lane & 15, quad = lane >> 4;
  const int wm = (wave & 1) * 64, wn = (wave >> 1) * 64;

  const short* Ab = xb + (size_t)mt * 128 * CC;
  const short* Bb = Wbt + ((size_t)wsel * CC + nc0) * CC;

  f32x4 acc[16];
  #pragma unroll
  for (int i = 0; i < 16; ++i) acc[i] = f32x4{0.f, 0.f, 0.f, 0.f};

  for (int kt = 0; kt < 12; ++kt) {
    const int k0 = kt * 32;
    __syncthreads();
    #pragma unroll
    for (int c = 0; c < 2; ++c) {
      const int ci = c * 256 + tid;      // 16B-chunk index, 0..511
      const int m = ci >> 2, p = ci & 3;
      const bf16x8 av = *(const bf16x8*)(Ab + (size_t)m * CC + k0 + p * 8);
      *(bf16x8*)((char*)As + m * 80 + p * 16) = av;
      const bf16x8 bv = *(const bf16x8*)(Bb + (size_t)m * CC + k0 + p * 8);
      *(bf16x8*)((char*)Bs + m * 80 + p * 16) = bv;
    }
    __syncthreads();
    bf16x8 af[4], bf[4];
    #pragma unroll
    for (int i = 0; i < 4; ++i) {
      af[i] = *(const bf16x8*)((char*)As + (wm + i * 16 + l15) * 80 + quad * 16);
      bf[i] = *(const bf16x8*)((char*)Bs + (wn + i * 16 + l15) * 80 + quad * 16);
    }
    #pragma unroll
    for (int i = 0; i < 4; ++i)
      #pragma unroll
      for (int j = 0; j < 4; ++j)
        acc[i * 4 + j] =
            __builtin_amdgcn_mfma_f32_16x16x32_bf16(af[i], bf[j], acc[i * 4 + j], 0, 0, 0);
  }

  if (nt < 6) {
    short* O = (nt < 3) ? Q : K;
    #pragma unroll
    for (int i = 0; i < 4; ++i)
      #pragma unroll
      for (int j = 0; j < 4; ++j) {
        const f32x4 a = acc[i * 4 + j];
        const int r0 = mt * 128 + wm + i * 16 + quad * 4;
        const int c = nc0 + wn + j * 16 + l15;
        #pragma unroll
        for (int r = 0; r < 4; ++r) O[(size_t)(r0 + r) * CC + c] = f2bf(a[r]);
      }
  } else {
    __syncthreads();                     // done with As/Bs; reuse as Es
    #pragma unroll
    for (int i = 0; i < 4; ++i)
      #pragma unroll
      for (int j = 0; j < 4; ++j) {
        const f32x4 a = acc[i * 4 + j];
        const int dl = wn + j * 16 + l15;       // local col (d)
        const int ml = wm + i * 16 + quad * 4;  // local row (t)
        short4 p4;
        p4.x = f2bf(a[0]); p4.y = f2bf(a[1]); p4.z = f2bf(a[2]); p4.w = f2bf(a[3]);
        *(short4*)(Es + (size_t)dl * 136 + ml) = p4;
      }
    __syncthreads();
    const int d0 = (nt - 6) * 128;
    const int b = mt >> 4, t0 = (mt & 15) * 128;
    const int dr = tid >> 1, hf = tid & 1;
    const short* src = Es + (size_t)dr * 136 + hf * 64;
    short* dst = Vt + ((size_t)b * CC + d0 + dr) * TT + t0 + hf * 64;
    #pragma unroll
    for (int c = 0; c < 8; ++c)          // FIX: 8 chunks = 64 shorts per thread
      *(bf16x8*)(dst + c * 8) = *(const bf16x8*)(src + c * 8);
  }
}

// ---------------------------------------------------------------------------
// Flash attention, causal. Block = 64 queries / 4 waves; per-chunk (32 keys)
// K and Vt tiles staged in LDS (coalesced global, padded rows), fragments
// via ds_read_b128. exp2-domain online softmax. Wave-uniform mask skip.
// ---------------------------------------------------------------------------
__global__ __launch_bounds__(256, 2)
void attn_kernel(const short* __restrict__ Q, const short* __restrict__ K,
                 const short* __restrict__ Vt, float* __restrict__ out) {
  __shared__ char sm[60928];
  short* Ks = (short*)sm;                   // [32 keys][392]   rows 784 B
  short* Vs = (short*)(sm + 25088);         // [384 d][40]      rows 80 B
  short* Ps = (short*)(sm + 55808);         // [4 waves][16][40]

  const int blk = blockIdx.x;
  const int b   = blk / (TT / 64);
  const int q0b = (blk % (TT / 64)) * 64;
  const int tid = threadIdx.x;
  const int wave = tid >> 6, lane = tid & 63;
  const int l15 = lane & 15, quad = lane >> 4;
  const int q0 = q0b + wave * 16;
  short* pw = Ps + wave * 640;

  // Q fragments resident in registers (scattered load, once)
  bf16x8 qf[12];
  const short* qp = Q + ((size_t)b * TT + q0 + l15) * CC + quad * 8;
  #pragma unroll
  for (int ks = 0; ks < 12; ++ks) qf[ks] = *(const bf16x8*)(qp + ks * 32);

  f32x4 o[24];
  #pragma unroll
  for (int n = 0; n < 24; ++n) o[n] = f32x4{0.f, 0.f, 0.f, 0.f};
  float m[4], l[4];
  #pragma unroll
  for (int r = 0; r < 4; ++r) { m[r] = -INFINITY; l[r] = 0.f; }

  const float scale2 = 0.051031036307982884f * 1.4426950408889634f; // C^-.5*log2e
  const short* kb  = K  + (size_t)b * TT * CC;
  const short* vtb = Vt + (size_t)b * CC * TT;
  const int nchunk = q0b / 32 + 2;

  for (int kc = 0; kc < nchunk; ++kc) {
    const int k0 = kc * 32;
    __syncthreads();
    // ---- stage K chunk [32][384] and Vt chunk [384][32] (1536 16B chunks ea)
    #pragma unroll
    for (int c = 0; c < 6; ++c) {
      const int ci = c * 256 + tid;
      const int kk = ci / 48, kp = ci % 48;
      const bf16x8 kv = *(const bf16x8*)(kb + (size_t)(k0 + kk) * CC + kp * 8);
      *(bf16x8*)((char*)Ks + kk * 784 + kp * 16) = kv;
      const int d = ci >> 2, pv = ci & 3;
      const bf16x8 vv = *(const bf16x8*)(vtb + (size_t)d * TT + k0 + pv * 8);
      *(bf16x8*)((char*)Vs + d * 80 + pv * 16) = vv;
    }
    __syncthreads();
    if (k0 > q0 + 15) continue;            // fully masked for this wave

    // ---- S = Q K^T (16 q x 32 keys)
    f32x4 s0 = f32x4{0.f, 0.f, 0.f, 0.f};
    f32x4 s1 = f32x4{0.f, 0.f, 0.f, 0.f};
    #pragma unroll
    for (int ks = 0; ks < 12; ++ks) {
      const bf16x8 b0 = *(const bf16x8*)((char*)Ks + l15 * 784 + (ks * 4 + quad) * 16);
      const bf16x8 b1 = *(const bf16x8*)((char*)Ks + (16 + l15) * 784 + (ks * 4 + quad) * 16);
      s0 = __builtin_amdgcn_mfma_f32_16x16x32_bf16(qf[ks], b0, s0, 0, 0, 0);
      s1 = __builtin_amdgcn_mfma_f32_16x16x32_bf16(qf[ks], b1, s1, 0, 0, 0);
    }
    // ---- scale (log2 domain) + causal mask + row max
    const bool domask = (k0 + 31 > q0);
    float mx[4];
    #pragma unroll
    for (int r = 0; r < 4; ++r) {
      float a = s0[r] * scale2;
      float c = s1[r] * scale2;
      if (domask) {
        const int qg = q0 + quad * 4 + r;
        if (k0 + l15 > qg)      a = -INFINITY;
        if (k0 + 16 + l15 > qg) c = -INFINITY;
      }
      s0[r] = a; s1[r] = c;
      float v = fmaxf(a, c);
      v = fmaxf(v, __shfl_xor(v, 1));
      v = fmaxf(v, __shfl_xor(v, 2));
      v = fmaxf(v, __shfl_xor(v, 4));
      v = fmaxf(v, __shfl_xor(v, 8));
      mx[r] = v;
    }
    // ---- online softmax update (exp2 domain)
    float alpha[4];
    #pragma unroll
    for (int r = 0; r < 4; ++r) {
      const float mn = fmaxf(m[r], mx[r]);
      alpha[r] = exp2f(m[r] - mn);
      m[r] = mn;
      const float p0 = exp2f(s0[r] - mn);
      const float p1 = exp2f(s1[r] - mn);
      s0[r] = p0; s1[r] = p1;
      float rs = p0 + p1;
      rs += __shfl_xor(rs, 1);
      rs += __shfl_xor(rs, 2);
      rs += __shfl_xor(rs, 4);
      rs += __shfl_xor(rs, 8);
      l[r] = l[r] * alpha[r] + rs;
    }
    const bool need = (alpha[0] < 1.f) | (alpha[1] < 1.f) |
                      (alpha[2] < 1.f) | (alpha[3] < 1.f);
    if (__any(need)) {
      #pragma unroll
      for (int n = 0; n < 24; ++n) {
        #pragma unroll
        for (int r = 0; r < 4; ++r) o[n][r] *= alpha[r];
      }
    }
    // ---- P: C-layout -> A-layout via wave-private LDS
    #pragma unroll
    for (int r = 0; r < 4; ++r) {
      pw[(quad * 4 + r) * 40 + l15]      = f2bf(s0[r]);
      pw[(quad * 4 + r) * 40 + 16 + l15] = f2bf(s1[r]);
    }
    const bf16x8 pf = *(const bf16x8*)(pw + l15 * 40 + quad * 8);
    // ---- O += P V  (V fragments from LDS Vt tile)
    #pragma unroll
    for (int n = 0; n < 24; ++n) {
      const bf16x8 vf = *(const bf16x8*)((char*)Vs + (size_t)(n * 16 + l15) * 80 + quad * 16);
      o[n] = __builtin_amdgcn_mfma_f32_16x16x32_bf16(pf, vf, o[n], 0, 0, 0);
    }
  }

  // ---- epilogue
  float linv[4];
  #pragma unroll
  for (int r = 0; r < 4; ++r) linv[r] = 1.f / l[r];
  float* ob = out + ((size_t)b * TT + q0) * CC;
  #pragma unroll
  for (int n = 0; n < 24; ++n) {
    #pragma unroll
    for (int r = 0; r < 4; ++r) {
      ob[(size_t)(quad * 4 + r) * CC + n * 16 + l15] = o[n][r] * linv[r];
    }
  }
}

extern "C" void kernel_launch(void* const* d_in, const int* in_sizes, int n_in,
                              void* d_out, int out_size, void* d_ws, size_t ws_size,
                              hipStream_t stream) {
  const float* x  = (const float*)d_in[0];
  const float* Wq = (const float*)d_in[1];
  const float* Wk = (const float*)d_in[2];
  const float* Wv = (const float*)d_in[3];
  float* out = (float*)d_out;

  const size_t QS = (size_t)NB * TT * CC;     // 12.58M elems
  short* Qs = (short*)d_ws;
  short* Ks = Qs + QS;
  short* Vt = Ks + QS;                        // ws: 75.5 MB

  // bf16 staging lives in d_out (50 MB fp32) until attn overwrites it
  short* xb  = (short*)d_out;                 // 25.2 MB
  short* Wbt = xb + QS;                       // 0.9 MB

  hipLaunchKernelGGL(conv_x, dim3((int)(QS / 4 / 256)), dim3(256), 0, stream,
                     x, xb, (int)(QS / 4));
  hipLaunchKernelGGL(conv_wt, dim3(3 * CC), dim3(CC), 0, stream, Wq, Wk, Wv, Wbt);
  hipLaunchKernelGGL(proj_gemm, dim3(256 * 9), dim3(256), 0, stream,
                     xb, Wbt, Qs, Ks, Vt);
  hipLaunchKernelGGL(attn_kernel, dim3(NB * TT / 64), dim3(256), 0, stream,
                     Qs, Ks, Vt, out);
}

// Round 4
// 416.105 us; speedup vs baseline: 3.5919x; 1.1094x over previous
//
#include <hip/hip_runtime.h>
#include <hip/hip_bf16.h>

#define NB 16
#define TT 2048
#define CC 384

typedef short bf16x8 __attribute__((ext_vector_type(8)));
typedef float f32x4 __attribute__((ext_vector_type(4)));

static __device__ __forceinline__ short f2bf(float f) {
  union { __hip_bfloat16 h; short s; } u;
  u.h = __float2bfloat16(f);
  return u.s;
}

// C^-0.5 * log2(e): folded into Q at projection time (attn works in exp2 domain)
#define QSC (0.051031036307982884f * 1.4426950408889634f)

// ---------------------------------------------------------------------------
// W[3] (fp32 [C][H]) -> Wbt (bf16 [3][n=H][k=C])  (transposed for LDS staging)
// ---------------------------------------------------------------------------
__global__ __launch_bounds__(384)
void conv_wt(const float* __restrict__ Wq, const float* __restrict__ Wk,
             const float* __restrict__ Wv, short* __restrict__ Wbt) {
  const int w = blockIdx.x / CC;
  const int n = blockIdx.x % CC;
  const int k = threadIdx.x;
  const float* W = (w == 0) ? Wq : (w == 1) ? Wk : Wv;
  Wbt[((size_t)w * CC + n) * CC + k] = f2bf(W[(size_t)k * CC + n]);
}

// ---------------------------------------------------------------------------
// Fused QKV projection GEMM: [32768 x 384](fp32 x, converted in-reg) x
// [384 x 1152] bf16 MFMA, register-prefetch pipelined.
// n-tiles 0-2 -> Q (pre-scaled by QSC), 3-5 -> K, 6-8 -> V transposed to
// Vt[b][d][t] via LDS transpose epilogue.
// ---------------------------------------------------------------------------
__global__ __launch_bounds__(256, 3)
void proj_gemm(const float* __restrict__ x, const short* __restrict__ Wbt,
               short* __restrict__ Q, short* __restrict__ K,
               short* __restrict__ Vt) {
  __shared__ char smem[34816];           // staging (2x10240) U epilogue (34816)
  short* As = (short*)smem;              // [128][40] shorts (32 data + 8 pad)
  short* Bs = (short*)(smem + 10240);    // [128][40]
  short* Es = (short*)smem;              // epilogue [128][136]

  const int mt = blockIdx.x & 255;
  const int nt = blockIdx.x >> 8;        // 0..8
  const int wsel = nt / 3;               // 0=Q,1=K,2=V
  const int nc0 = (nt % 3) * 128;
  const int tid = threadIdx.x;
  const int wave = tid >> 6, lane = tid & 63;
  const int l15 = lane & 15, quad = lane >> 4;
  const int wm = (wave & 1) * 64, wn = (wave >> 1) * 64;

  const float* Ab = x + (size_t)mt * 128 * CC;
  const short* Bb = Wbt + ((size_t)wsel * CC + nc0) * CC;

  f32x4 acc[16];
  #pragma unroll
  for (int i = 0; i < 16; ++i) acc[i] = f32x4{0.f, 0.f, 0.f, 0.f};

  // prefetch registers
  float4 ra[4];
  bf16x8 rb[2];
  #pragma unroll
  for (int c = 0; c < 4; ++c) {
    const int ci = c * 256 + tid;        // float4-chunk, 0..1023
    ra[c] = *(const float4*)(Ab + (size_t)(ci >> 3) * CC + (ci & 7) * 4);
  }
  #pragma unroll
  for (int c = 0; c < 2; ++c) {
    const int ci = c * 256 + tid;        // 16B-chunk, 0..511
    rb[c] = *(const bf16x8*)(Bb + (size_t)(ci >> 2) * CC + (ci & 3) * 8);
  }

  for (int kt = 0; kt < 12; ++kt) {
    __syncthreads();
    #pragma unroll
    for (int c = 0; c < 4; ++c) {
      const int ci = c * 256 + tid;
      short4 s4;
      s4.x = f2bf(ra[c].x); s4.y = f2bf(ra[c].y);
      s4.z = f2bf(ra[c].z); s4.w = f2bf(ra[c].w);
      *(short4*)((char*)As + (ci >> 3) * 80 + (ci & 7) * 8) = s4;
    }
    #pragma unroll
    for (int c = 0; c < 2; ++c) {
      const int ci = c * 256 + tid;
      *(bf16x8*)((char*)Bs + (ci >> 2) * 80 + (ci & 3) * 16) = rb[c];
    }
    __syncthreads();
    if (kt < 11) {
      const int k0 = (kt + 1) * 32;
      #pragma unroll
      for (int c = 0; c < 4; ++c) {
        const int ci = c * 256 + tid;
        ra[c] = *(const float4*)(Ab + (size_t)(ci >> 3) * CC + k0 + (ci & 7) * 4);
      }
      #pragma unroll
      for (int c = 0; c < 2; ++c) {
        const int ci = c * 256 + tid;
        rb[c] = *(const bf16x8*)(Bb + (size_t)(ci >> 2) * CC + k0 + (ci & 3) * 8);
      }
    }
    bf16x8 af[4], bf[4];
    #pragma unroll
    for (int i = 0; i < 4; ++i) {
      af[i] = *(const bf16x8*)((char*)As + (wm + i * 16 + l15) * 80 + quad * 16);
      bf[i] = *(const bf16x8*)((char*)Bs + (wn + i * 16 + l15) * 80 + quad * 16);
    }
    #pragma unroll
    for (int i = 0; i < 4; ++i)
      #pragma unroll
      for (int j = 0; j < 4; ++j)
        acc[i * 4 + j] =
            __builtin_amdgcn_mfma_f32_16x16x32_bf16(af[i], bf[j], acc[i * 4 + j], 0, 0, 0);
  }

  if (nt < 6) {
    short* O = (nt < 3) ? Q : K;
    const float sc = (nt < 3) ? QSC : 1.0f;
    #pragma unroll
    for (int i = 0; i < 4; ++i)
      #pragma unroll
      for (int j = 0; j < 4; ++j) {
        const f32x4 a = acc[i * 4 + j];
        const int r0 = mt * 128 + wm + i * 16 + quad * 4;
        const int c = nc0 + wn + j * 16 + l15;
        #pragma unroll
        for (int r = 0; r < 4; ++r) O[(size_t)(r0 + r) * CC + c] = f2bf(a[r] * sc);
      }
  } else {
    __syncthreads();                     // done with As/Bs; reuse as Es
    #pragma unroll
    for (int i = 0; i < 4; ++i)
      #pragma unroll
      for (int j = 0; j < 4; ++j) {
        const f32x4 a = acc[i * 4 + j];
        const int dl = wn + j * 16 + l15;       // local col (d)
        const int ml = wm + i * 16 + quad * 4;  // local row (t)
        short4 p4;
        p4.x = f2bf(a[0]); p4.y = f2bf(a[1]); p4.z = f2bf(a[2]); p4.w = f2bf(a[3]);
        *(short4*)(Es + (size_t)dl * 136 + ml) = p4;
      }
    __syncthreads();
    const int d0 = (nt - 6) * 128;
    const int b = mt >> 4, t0 = (mt & 15) * 128;
    const int dr = tid >> 1, hf = tid & 1;
    const short* src = Es + (size_t)dr * 136 + hf * 64;
    short* dst = Vt + ((size_t)b * CC + d0 + dr) * TT + t0 + hf * 64;
    #pragma unroll
    for (int c = 0; c < 8; ++c)
      *(bf16x8*)(dst + c * 8) = *(const bf16x8*)(src + c * 8);
  }
}

// ---------------------------------------------------------------------------
// Flash attention, causal. Block = 64 queries / 4 waves, 32-key chunks,
// register-prefetch pipelined LDS staging (padded rows), l-sum via ones-MFMA.
// Grid ordered longest-block-first; blk%8 = batch%8 for XCD L2 locality.
// ---------------------------------------------------------------------------
__global__ __launch_bounds__(256, 2)
void attn_kernel(const short* __restrict__ Q, const short* __restrict__ K,
                 const short* __restrict__ Vt, float* __restrict__ out) {
  __shared__ char sm[60928];
  short* Ks = (short*)sm;                   // [32 keys][392]   rows 784 B
  short* Vs = (short*)(sm + 25088);         // [384 d][40]      rows 80 B
  short* Ps = (short*)(sm + 55808);         // [4 waves][16][40]

  const int blk = blockIdx.x;
  const int qt  = 31 - (blk >> 4);          // descending work order
  const int b   = blk & 15;                 // XCD = blk%8 = b%8
  const int q0b = qt * 64;
  const int tid = threadIdx.x;
  const int wave = tid >> 6, lane = tid & 63;
  const int l15 = lane & 15, quad = lane >> 4;
  const int q0 = q0b + wave * 16;
  short* pw = Ps + wave * 640;

  // Q fragments resident in registers (Q pre-scaled by QSC)
  bf16x8 qf[12];
  const short* qp = Q + ((size_t)b * TT + q0 + l15) * CC + quad * 8;
  #pragma unroll
  for (int ks = 0; ks < 12; ++ks) qf[ks] = *(const bf16x8*)(qp + ks * 32);

  f32x4 o[24];
  #pragma unroll
  for (int n = 0; n < 24; ++n) o[n] = f32x4{0.f, 0.f, 0.f, 0.f};
  f32x4 lsum = f32x4{0.f, 0.f, 0.f, 0.f};
  float m[4];
  #pragma unroll
  for (int r = 0; r < 4; ++r) m[r] = -INFINITY;

  bf16x8 onesf;
  #pragma unroll
  for (int i = 0; i < 8; ++i) onesf[i] = (short)0x3F80;   // bf16 1.0

  const short* kb  = K  + (size_t)b * TT * CC;
  const short* vtb = Vt + (size_t)b * CC * TT;
  const int nchunk = qt * 2 + 2;

  // prefetch chunk 0
  bf16x8 rk[6], rv[6];
  #pragma unroll
  for (int c = 0; c < 6; ++c) {
    const int ci = c * 256 + tid;
    rk[c] = *(const bf16x8*)(kb + (size_t)(ci / 48) * CC + (ci % 48) * 8);
    rv[c] = *(const bf16x8*)(vtb + (size_t)(ci >> 2) * TT + (ci & 3) * 8);
  }

  for (int kc = 0; kc < nchunk; ++kc) {
    const int k0 = kc * 32;
    __syncthreads();                       // all waves done reading prev chunk
    #pragma unroll
    for (int c = 0; c < 6; ++c) {
      const int ci = c * 256 + tid;
      *(bf16x8*)((char*)Ks + (ci / 48) * 784 + (ci % 48) * 16) = rk[c];
      *(bf16x8*)((char*)Vs + (ci >> 2) * 80 + (ci & 3) * 16) = rv[c];
    }
    __syncthreads();
    if (kc + 1 < nchunk) {                 // issue next chunk's loads now
      const int kn = k0 + 32;
      #pragma unroll
      for (int c = 0; c < 6; ++c) {
        const int ci = c * 256 + tid;
        rk[c] = *(const bf16x8*)(kb + (size_t)(kn + ci / 48) * CC + (ci % 48) * 8);
        rv[c] = *(const bf16x8*)(vtb + (size_t)(ci >> 2) * TT + kn + (ci & 3) * 8);
      }
    }
    if (k0 > q0 + 15) continue;            // fully masked for this wave

    // ---- S = Q K^T (16 q x 32 keys), already in log2 domain via Q scaling
    f32x4 s0 = f32x4{0.f, 0.f, 0.f, 0.f};
    f32x4 s1 = f32x4{0.f, 0.f, 0.f, 0.f};
    #pragma unroll
    for (int ks = 0; ks < 12; ++ks) {
      const bf16x8 b0 = *(const bf16x8*)((char*)Ks + l15 * 784 + (ks * 4 + quad) * 16);
      const bf16x8 b1 = *(const bf16x8*)((char*)Ks + (16 + l15) * 784 + (ks * 4 + quad) * 16);
      s0 = __builtin_amdgcn_mfma_f32_16x16x32_bf16(qf[ks], b0, s0, 0, 0, 0);
      s1 = __builtin_amdgcn_mfma_f32_16x16x32_bf16(qf[ks], b1, s1, 0, 0, 0);
    }
    // ---- causal mask + row max (shuffles within 16-lane col groups)
    const bool domask = (k0 + 31 > q0);
    float mx[4];
    #pragma unroll
    for (int r = 0; r < 4; ++r) {
      float a = s0[r], c = s1[r];
      if (domask) {
        const int qg = q0 + quad * 4 + r;
        if (k0 + l15 > qg)      a = -INFINITY;
        if (k0 + 16 + l15 > qg) c = -INFINITY;
      }
      s0[r] = a; s1[r] = c;
      float v = fmaxf(a, c);
      v = fmaxf(v, __shfl_xor(v, 1));
      v = fmaxf(v, __shfl_xor(v, 2));
      v = fmaxf(v, __shfl_xor(v, 4));
      v = fmaxf(v, __shfl_xor(v, 8));
      mx[r] = v;
    }
    // ---- online softmax update (exp2 domain); row-sum comes from ones-MFMA
    float alpha[4];
    #pragma unroll
    for (int r = 0; r < 4; ++r) {
      const float mn = fmaxf(m[r], mx[r]);
      alpha[r] = exp2f(m[r] - mn);
      m[r] = mn;
      s0[r] = exp2f(s0[r] - mn);
      s1[r] = exp2f(s1[r] - mn);
    }
    const bool need = (alpha[0] < 1.f) | (alpha[1] < 1.f) |
                      (alpha[2] < 1.f) | (alpha[3] < 1.f);
    if (__any(need)) {
      #pragma unroll
      for (int r = 0; r < 4; ++r) lsum[r] *= alpha[r];
      #pragma unroll
      for (int n = 0; n < 24; ++n) {
        #pragma unroll
        for (int r = 0; r < 4; ++r) o[n][r] *= alpha[r];
      }
    }
    // ---- P: C-layout -> A-layout via wave-private LDS
    #pragma unroll
    for (int r = 0; r < 4; ++r) {
      pw[(quad * 4 + r) * 40 + l15]      = f2bf(s0[r]);
      pw[(quad * 4 + r) * 40 + 16 + l15] = f2bf(s1[r]);
    }
    const bf16x8 pf = *(const bf16x8*)(pw + l15 * 40 + quad * 8);
    // ---- l += P . 1 (one MFMA replaces the shuffle-sum chain)
    lsum = __builtin_amdgcn_mfma_f32_16x16x32_bf16(pf, onesf, lsum, 0, 0, 0);
    // ---- O += P V
    #pragma unroll
    for (int n = 0; n < 24; ++n) {
      const bf16x8 vf = *(const bf16x8*)((char*)Vs + (size_t)(n * 16 + l15) * 80 + quad * 16);
      o[n] = __builtin_amdgcn_mfma_f32_16x16x32_bf16(pf, vf, o[n], 0, 0, 0);
    }
  }

  // ---- epilogue
  float linv[4];
  #pragma unroll
  for (int r = 0; r < 4; ++r) linv[r] = 1.f / lsum[r];
  float* ob = out + ((size_t)b * TT + q0) * CC;
  #pragma unroll
  for (int n = 0; n < 24; ++n) {
    #pragma unroll
    for (int r = 0; r < 4; ++r) {
      ob[(size_t)(quad * 4 + r) * CC + n * 16 + l15] = o[n][r] * linv[r];
    }
  }
}

extern "C" void kernel_launch(void* const* d_in, const int* in_sizes, int n_in,
                              void* d_out, int out_size, void* d_ws, size_t ws_size,
                              hipStream_t stream) {
  const float* x  = (const float*)d_in[0];
  const float* Wq = (const float*)d_in[1];
  const float* Wk = (const float*)d_in[2];
  const float* Wv = (const float*)d_in[3];
  float* out = (float*)d_out;

  const size_t QS = (size_t)NB * TT * CC;     // 12.58M elems
  short* Qs = (short*)d_ws;
  short* Ks = Qs + QS;
  short* Vt = Ks + QS;                        // ws: 75.5 MB

  // bf16 W^T staging lives in d_out (50 MB fp32) until attn overwrites it
  short* Wbt = (short*)d_out;                 // 0.9 MB

  hipLaunchKernelGGL(conv_wt, dim3(3 * CC), dim3(CC), 0, stream, Wq, Wk, Wv, Wbt);
  hipLaunchKernelGGL(proj_gemm, dim3(256 * 9), dim3(256), 0, stream,
                     x, Wbt, Qs, Ks, Vt);
  hipLaunchKernelGGL(attn_kernel, dim3(NB * TT / 64), dim3(256), 0, stream,
                     Qs, Ks, Vt, out);
}